// Round 3
// baseline (3765.498 us; speedup 1.0000x reference)
//
#include <hip/hip_runtime.h>
#include <cstdint>
#include <cstddef>

// Problem constants (match reference)
#define NB 8          // B clouds
#define NP 4096       // N points per cloud
#define NC 64         // C feature channels
#define NM 2048       // M sampled centroids
#define NK 64         // K max neighbors
#define H1 64
#define H2 64
#define NOUT 128
#define CAND_CAP 1024
#define MSG_LD 68     // padded LDS leading dim (17*16B -> float4-aligned rows)

static __device__ __forceinline__ float sq3(float x, float y, float z) {
    // ((x*x + y*y) + z*z) with no FMA contraction, matching numpy order
    return __fadd_rn(__fadd_rn(__fmul_rn(x, x), __fmul_rn(y, y)), __fmul_rn(z, z));
}

// ---------------------------------------------------------------------------
// Kernel 1: exact FPS per cloud (8 blocks x 512 threads).
// Points live in registers (8/thread). The reduction carries the winning
// point's coordinates, so no dependent LDS lookup of pts[last] is needed.
// ---------------------------------------------------------------------------
__global__ __launch_bounds__(512, 1)
void fps_kernel(const float* __restrict__ pos,
                float4* __restrict__ p4,
                float* __restrict__ pos_s,
                float* __restrict__ batch_s)
{
    __shared__ float4 pts[NP];                  // 64 KB (staging + output stage)
    __shared__ int s_idx[NM];                   // 8 KB
    __shared__ unsigned long long redk[2][8];
    __shared__ float4 redc[2][8];

    const int b = blockIdx.x;
    const int t = threadIdx.x;
    const float* p = pos + (size_t)b * NP * 3;

    for (int j = t; j < NP; j += 512) {
        float x = p[j * 3 + 0], y = p[j * 3 + 1], z = p[j * 3 + 2];
        float4 q = make_float4(x, y, z, sq3(x, y, z));
        pts[j] = q;
        p4[b * NP + j] = q;
    }
    if (t == 0) s_idx[0] = 0;
    __syncthreads();

    // thread t owns points j = t + i*512, i in 0..7 (ascending i == ascending j)
    float rx[8], ry[8], rz[8], md[8];
#pragma unroll
    for (int i = 0; i < 8; ++i) {
        float4 q = pts[t + (i << 9)];
        rx[i] = q.x; ry[i] = q.y; rz[i] = q.z;
        md[i] = __builtin_inff();
    }

    float4 L0 = pts[0];
    float Lx = L0.x, Ly = L0.y, Lz = L0.z;

    for (int m = 1; m < NM; ++m) {
        float vv[8];
#pragma unroll
        for (int i = 0; i < 8; ++i) {
            float dx = __fsub_rn(rx[i], Lx);
            float dy = __fsub_rn(ry[i], Ly);
            float dz = __fsub_rn(rz[i], Lz);
            float d = sq3(dx, dy, dz);
            float v = fminf(md[i], d);
            md[i] = v;
            vv[i] = v;
        }
        // pairwise argmax tree; strict '>' keeps the smaller index on ties
        float nv[4], nx[4], ny[4], nz[4]; unsigned nj[4];
#pragma unroll
        for (int i = 0; i < 4; ++i) {
            bool c = vv[2 * i + 1] > vv[2 * i];
            nv[i] = c ? vv[2 * i + 1] : vv[2 * i];
            nj[i] = (unsigned)(t + ((2 * i + (c ? 1 : 0)) << 9));
            nx[i] = c ? rx[2 * i + 1] : rx[2 * i];
            ny[i] = c ? ry[2 * i + 1] : ry[2 * i];
            nz[i] = c ? rz[2 * i + 1] : rz[2 * i];
        }
        float mv[2], mx2[2], my2[2], mz2[2]; unsigned mj[2];
#pragma unroll
        for (int i = 0; i < 2; ++i) {
            bool c = nv[2 * i + 1] > nv[2 * i];
            mv[i] = c ? nv[2 * i + 1] : nv[2 * i];
            mj[i] = c ? nj[2 * i + 1] : nj[2 * i];
            mx2[i] = c ? nx[2 * i + 1] : nx[2 * i];
            my2[i] = c ? ny[2 * i + 1] : ny[2 * i];
            mz2[i] = c ? nz[2 * i + 1] : nz[2 * i];
        }
        bool cf = mv[1] > mv[0];
        float fv = cf ? mv[1] : mv[0];
        unsigned fj = cf ? mj[1] : mj[0];
        float fx = cf ? mx2[1] : mx2[0];
        float fy = cf ? my2[1] : my2[0];
        float fz = cf ? mz2[1] : mz2[0];

        // key: larger value wins; on tie, smaller j wins (argmax semantics)
        unsigned long long key =
            ((unsigned long long)__float_as_uint(fv) << 32) |
            (unsigned long long)(0xFFFFFFFFu - fj);
#pragma unroll
        for (int o = 32; o > 0; o >>= 1) {
            unsigned long long ok = __shfl_xor(key, o, 64);
            float ox = __shfl_xor(fx, o, 64);
            float oy = __shfl_xor(fy, o, 64);
            float oz = __shfl_xor(fz, o, 64);
            if (ok > key) { key = ok; fx = ox; fy = oy; fz = oz; }
        }
        const int par = m & 1;
        if ((t & 63) == 0) {
            int w = t >> 6;
            redk[par][w] = key;
            redc[par][w] = make_float4(fx, fy, fz, 0.f);
        }
        __syncthreads();
        unsigned long long gk = redk[par][0];
        float4 gc = redc[par][0];
#pragma unroll
        for (int w = 1; w < 8; ++w) {
            unsigned long long k2 = redk[par][w];
            float4 c2 = redc[par][w];
            if (k2 > gk) { gk = k2; gc = c2; }
        }
        Lx = gc.x; Ly = gc.y; Lz = gc.z;
        if (t == 0) s_idx[m] = (int)(0xFFFFFFFFu - (unsigned)(gk & 0xFFFFFFFFull));
        // red ping-pongs on parity; one barrier per iteration is race-free
    }
    __syncthreads();

    for (int m = t; m < NM; m += 512) {
        int j = s_idx[m];
        size_t o = (size_t)(b * NM + m);
        float4 q = pts[j];
        pos_s[o * 3 + 0] = q.x;
        pos_s[o * 3 + 1] = q.y;
        pos_s[o * 3 + 2] = q.z;
        batch_s[o] = (float)b;
    }
}

// ---------------------------------------------------------------------------
// Kernel 2: radius ball query + exact K-nearest-within-R set per centroid.
// One wave per centroid; 4 waves per block. Selection = binary search on the
// distance-bit threshold (output order is irrelevant: result is max-pooled).
// ---------------------------------------------------------------------------
__global__ __launch_bounds__(256, 1)
void ball_kernel(const float4* __restrict__ p4,
                 const float* __restrict__ pos_s,
                 int* __restrict__ nbr,
                 int* __restrict__ cnt_out)
{
    __shared__ unsigned long long cand[4][CAND_CAP];
    const float R2 = 0.04f;  // f32(R*R)

    const int wv = threadIdx.x >> 6;
    const int lane = threadIdx.x & 63;
    const int c = blockIdx.x * 4 + wv;         // centroid id in [0, B*M)
    const int b = c >> 11;                     // / NM
    const float4* pc = p4 + b * NP;

    const float sx = pos_s[c * 3 + 0];
    const float sy = pos_s[c * 3 + 1];
    const float sz = pos_s[c * 3 + 2];
    const float ps2 = sq3(sx, sy, sz);

    int n = 0;
    for (int j0 = 0; j0 < NP; j0 += 64) {
        int j = j0 + lane;
        float4 q = pc[j];
        float dot = __fadd_rn(__fadd_rn(__fmul_rn(sx, q.x), __fmul_rn(sy, q.y)),
                              __fmul_rn(sz, q.z));
        float d2 = __fsub_rn(__fadd_rn(ps2, q.w), __fmul_rn(2.0f, dot));
        d2 = fmaxf(d2, 0.0f);
        bool in = (d2 <= R2);
        unsigned long long mask = __ballot(in);
        if (in) {
            int off = __popcll(mask & ((1ull << lane) - 1ull));
            int slot = n + off;
            if (slot < CAND_CAP)
                cand[wv][slot] =
                    ((unsigned long long)__float_as_uint(d2) << 32) |
                    (unsigned long long)(unsigned)j;
        }
        n += __popcll(mask);
    }
    if (n > CAND_CAP) n = CAND_CAP;

    int* nb = nbr + (size_t)c * NK;
    if (n <= NK) {
        for (int i = lane; i < n; i += 64)
            nb[i] = (int)(cand[wv][i] & 0xFFFFFFFFull);
        if (lane == 0) cnt_out[c] = n;
    } else if (n <= 256) {
        // 4 register-resident candidates per lane; invalid slots = all-ones
        unsigned long long k0 = cand[wv][lane];               // n > 64 -> valid
        unsigned long long k1 = (lane + 64  < n) ? cand[wv][lane + 64]  : ~0ull;
        unsigned long long k2 = (lane + 128 < n) ? cand[wv][lane + 128] : ~0ull;
        unsigned long long k3 = (lane + 192 < n) ? cand[wv][lane + 192] : ~0ull;
        unsigned d0 = (unsigned)(k0 >> 32), d1 = (unsigned)(k1 >> 32);
        unsigned d2b = (unsigned)(k2 >> 32), d3 = (unsigned)(k3 >> 32);

        // binary search: D = 64th smallest distance-bit value
        unsigned lo = 0u, hi = __float_as_uint(R2) + 1u;  // f(lo)<64 <= f(hi)=n
        while (hi - lo > 1u) {
            unsigned mid = (lo + hi) >> 1;
            int cc = (int)(d0 < mid) + (int)(d1 < mid) +
                     (int)(d2b < mid) + (int)(d3 < mid);
            int tot = __popcll(__ballot(cc > 0)) + __popcll(__ballot(cc > 1)) +
                      __popcll(__ballot(cc > 2)) + __popcll(__ballot(cc > 3));
            if (tot >= NK) hi = mid; else lo = mid;
        }
        const unsigned D = lo;
        bool l0 = d0 < D, l1 = d1 < D, l2 = d2b < D, l3 = d3 < D;
        bool e0 = d0 == D, e1 = d1 == D, e2 = d2b == D, e3 = d3 == D;
        int mcnt = __popcll(__ballot(l0)) + __popcll(__ballot(l1)) +
                   __popcll(__ballot(l2)) + __popcll(__ballot(l3));
        int t64 = NK - mcnt;                       // take from equals, >= 1
        unsigned long long E0 = __ballot(e0), E1 = __ballot(e1);
        unsigned long long E2 = __ballot(e2), E3 = __ballot(e3);
        unsigned long long lt = (1ull << lane) - 1ull;
        int p0 = __popcll(E0), p1 = __popcll(E1), p2 = __popcll(E2);
        // equals ranked by array position == ascending point index (stable)
        bool t0 = e0 && (__popcll(E0 & lt) < t64);
        bool t1 = e1 && (p0 + __popcll(E1 & lt) < t64);
        bool t2 = e2 && (p0 + p1 + __popcll(E2 & lt) < t64);
        bool t3 = e3 && (p0 + p1 + p2 + __popcll(E3 & lt) < t64);
        bool i0 = l0 || t0, i1 = l1 || t1, i2 = l2 || t2, i3 = l3 || t3;
        unsigned long long M0 = __ballot(i0), M1 = __ballot(i1);
        unsigned long long M2 = __ballot(i2), M3 = __ballot(i3);
        int b1 = __popcll(M0), b2 = b1 + __popcll(M1), b3 = b2 + __popcll(M2);
        if (i0) nb[__popcll(M0 & lt)]      = (int)(k0 & 0xFFFFFFFFull);
        if (i1) nb[b1 + __popcll(M1 & lt)] = (int)(k1 & 0xFFFFFFFFull);
        if (i2) nb[b2 + __popcll(M2 & lt)] = (int)(k2 & 0xFFFFFFFFull);
        if (i3) nb[b3 + __popcll(M3 & lt)] = (int)(k3 & 0xFFFFFFFFull);
        if (lane == 0) cnt_out[c] = NK;
    } else {
        // fallback (unreachable for this data): 64 rounds of wave-wide min
        for (int r = 0; r < NK; ++r) {
            unsigned long long lmin = ~0ull;
            int lslot = -1;
            for (int i = lane; i < n; i += 64) {
                unsigned long long v = cand[wv][i];
                if (v < lmin) { lmin = v; lslot = i; }
            }
            unsigned long long gmin = lmin;
#pragma unroll
            for (int o = 32; o > 0; o >>= 1) {
                unsigned long long other = __shfl_xor(gmin, o, 64);
                gmin = (other < gmin) ? other : gmin;
            }
            if (lmin == gmin && lslot >= 0) {
                cand[wv][lslot] = ~0ull;
                nb[r] = (int)(gmin & 0xFFFFFFFFull);
            }
        }
        if (lane == 0) cnt_out[c] = NK;
    }
}

// ---------------------------------------------------------------------------
// Kernel 3: gather messages [x_j, pos_j - pos_i], 3-layer MLP (f32), masked
// max-pool. One block per centroid. LDS trimmed to ~71 KB (hB aliases msg,
// W3 read from L2) -> 2 blocks/CU.
// ---------------------------------------------------------------------------
__global__ __launch_bounds__(256, 2)
void mlp_kernel(const float* __restrict__ x,
                const float4* __restrict__ p4,
                const float* __restrict__ W1, const float* __restrict__ B1,
                const float* __restrict__ W2, const float* __restrict__ B2,
                const float* __restrict__ W3, const float* __restrict__ B3,
                const int* __restrict__ nbr, const int* __restrict__ cnt_arr,
                const float* __restrict__ pos_s,
                float* __restrict__ out)
{
    __shared__ __attribute__((aligned(16))) float sW1[67 * 64];
    __shared__ __attribute__((aligned(16))) float sW2[64 * 64];
    __shared__ float sB1[64], sB2[64], sB3[128];
    __shared__ __attribute__((aligned(16))) float msg[67 * MSG_LD]; // also hB
    __shared__ __attribute__((aligned(16))) float hA[64 * MSG_LD];
    __shared__ int obuf[128];
    __shared__ int s_nb[64];

    const int t = threadIdx.x;
    const int c = blockIdx.x;
    const int b = c >> 11;
    const int cnt = cnt_arr[c];
    float* hB = msg;   // msg is dead after layer 1; reuse for layer-2 output

    if (t < 128) obuf[t] = 0;
    if (t < 64) s_nb[t] = (t < cnt) ? nbr[(size_t)c * NK + t] : -1;
    {
        const float4* W1v = (const float4*)W1;
        const float4* W2v = (const float4*)W2;
        float4* s1 = (float4*)sW1;
        float4* s2 = (float4*)sW2;
        for (int i = t; i < 67 * 16; i += 256) s1[i] = W1v[i];
        for (int i = t; i < 64 * 16; i += 256) s2[i] = W2v[i];
    }
    if (t < 64) { sB1[t] = B1[t]; sB2[t] = B2[t]; }
    if (t < 128) sB3[t] = B3[t];
    const float sx = pos_s[c * 3 + 0];
    const float sy = pos_s[c * 3 + 1];
    const float sz = pos_s[c * 3 + 2];
    __syncthreads();

    // gather x_j -> msg[0..63][n], rel -> msg[64..66][n]
    {
        int n = t >> 2, q = t & 3;
        int j = s_nb[n];
        const float4* row = (const float4*)(x + ((size_t)b * NP + (j < 0 ? 0 : j)) * NC);
#pragma unroll
        for (int s = 0; s < 4; ++s) {
            int k4 = q * 4 + s;
            float4 v = (j >= 0) ? row[k4] : make_float4(0.f, 0.f, 0.f, 0.f);
            msg[(k4 * 4 + 0) * MSG_LD + n] = v.x;
            msg[(k4 * 4 + 1) * MSG_LD + n] = v.y;
            msg[(k4 * 4 + 2) * MSG_LD + n] = v.z;
            msg[(k4 * 4 + 3) * MSG_LD + n] = v.w;
        }
        if (t < 64) {
            int jj = s_nb[t];
            float rx = 0.f, ry = 0.f, rz = 0.f;
            if (jj >= 0) {
                float4 pj = p4[b * NP + jj];
                rx = __fsub_rn(pj.x, sx);
                ry = __fsub_rn(pj.y, sy);
                rz = __fsub_rn(pj.z, sz);
            }
            msg[64 * MSG_LD + t] = rx;
            msg[65 * MSG_LD + t] = ry;
            msg[66 * MSG_LD + t] = rz;
        }
    }
    __syncthreads();

    const int tn = (t >> 4) << 2;   // n0: 4 neighbors
    const int tf = (t & 15) << 2;   // f0: 4 features

    // ---- layer 1: [64n x 67k] @ [67k x 64f] -> hA
    {
        float acc[4][4];
#pragma unroll
        for (int i = 0; i < 4; ++i)
#pragma unroll
            for (int j = 0; j < 4; ++j) acc[i][j] = 0.f;
        for (int k = 0; k < 67; ++k) {
            float4 a = *(const float4*)&msg[k * MSG_LD + tn];
            float4 w = *(const float4*)&sW1[k * 64 + tf];
            float av[4] = {a.x, a.y, a.z, a.w};
            float wv[4] = {w.x, w.y, w.z, w.w};
#pragma unroll
            for (int i = 0; i < 4; ++i)
#pragma unroll
                for (int j = 0; j < 4; ++j)
                    acc[i][j] = fmaf(av[i], wv[j], acc[i][j]);
        }
#pragma unroll
        for (int j = 0; j < 4; ++j) {
            float bias = sB1[tf + j];
#pragma unroll
            for (int i = 0; i < 4; ++i)
                hA[(tf + j) * MSG_LD + (tn + i)] = fmaxf(acc[i][j] + bias, 0.f);
        }
    }
    __syncthreads();

    // ---- layer 2: [64n x 64k] @ [64k x 64f] -> hB (aliases msg)
    {
        float acc[4][4];
#pragma unroll
        for (int i = 0; i < 4; ++i)
#pragma unroll
            for (int j = 0; j < 4; ++j) acc[i][j] = 0.f;
        for (int k = 0; k < 64; ++k) {
            float4 a = *(const float4*)&hA[k * MSG_LD + tn];
            float4 w = *(const float4*)&sW2[k * 64 + tf];
            float av[4] = {a.x, a.y, a.z, a.w};
            float wv[4] = {w.x, w.y, w.z, w.w};
#pragma unroll
            for (int i = 0; i < 4; ++i)
#pragma unroll
                for (int j = 0; j < 4; ++j)
                    acc[i][j] = fmaf(av[i], wv[j], acc[i][j]);
        }
        __syncthreads();   // everyone done reading hA's producer msg... (L1 done)
#pragma unroll
        for (int j = 0; j < 4; ++j) {
            float bias = sB2[tf + j];
#pragma unroll
            for (int i = 0; i < 4; ++i)
                hB[(tf + j) * MSG_LD + (tn + i)] = fmaxf(acc[i][j] + bias, 0.f);
        }
    }
    __syncthreads();

    // ---- layer 3: [64n x 64k] @ [64k x 128f] + masked max-pool (W3 from L2)
    {
        const int tf3 = (t & 15) << 3;  // 8 features
        const float4* W3v = (const float4*)W3;
        const int wbase = (t & 15) << 1;
        float acc[4][8];
#pragma unroll
        for (int i = 0; i < 4; ++i)
#pragma unroll
            for (int j = 0; j < 8; ++j) acc[i][j] = 0.f;
#pragma unroll 4
        for (int k = 0; k < 64; ++k) {
            float4 a = *(const float4*)&hB[k * MSG_LD + tn];
            float4 w0 = W3v[k * 32 + wbase];
            float4 w1 = W3v[k * 32 + wbase + 1];
            float av[4] = {a.x, a.y, a.z, a.w};
            float wv[8] = {w0.x, w0.y, w0.z, w0.w, w1.x, w1.y, w1.z, w1.w};
#pragma unroll
            for (int i = 0; i < 4; ++i)
#pragma unroll
                for (int j = 0; j < 8; ++j)
                    acc[i][j] = fmaf(av[i], wv[j], acc[i][j]);
        }
#pragma unroll
        for (int j = 0; j < 8; ++j) {
            float bias = sB3[tf3 + j];
            float mx = -1.f;
#pragma unroll
            for (int i = 0; i < 4; ++i) {
                if (tn + i < cnt) {
                    float v = fmaxf(acc[i][j] + bias, 0.f);
                    mx = fmaxf(mx, v);
                }
            }
            if (mx >= 0.f) atomicMax(&obuf[tf3 + j], __float_as_int(mx));
        }
    }
    __syncthreads();
    if (t < 128) out[(size_t)c * NOUT + t] = __int_as_float(obuf[t]);
}

// ---------------------------------------------------------------------------
extern "C" void kernel_launch(void* const* d_in, const int* in_sizes, int n_in,
                              void* d_out, int out_size, void* d_ws, size_t ws_size,
                              hipStream_t stream)
{
    (void)in_sizes; (void)n_in; (void)out_size; (void)ws_size;
    const float* x   = (const float*)d_in[0];
    const float* pos = (const float*)d_in[1];
    // d_in[2] = batch (unused: batch[b][n] == b)
    const float* W1 = (const float*)d_in[3];
    const float* B1 = (const float*)d_in[4];
    const float* W2 = (const float*)d_in[5];
    const float* B2 = (const float*)d_in[6];
    const float* W3 = (const float*)d_in[7];
    const float* B3 = (const float*)d_in[8];

    float* out     = (float*)d_out;                       // [B,M,128]
    float* pos_s   = out + (size_t)NB * NM * NOUT;        // [B,M,3]
    float* batch_s = pos_s + (size_t)NB * NM * 3;         // [B,M]

    // workspace: p4 table (512 KB) | nbr (4 MB) | cnt (64 KB)  ~= 4.6 MB
    float4* p4 = (float4*)d_ws;
    int* nbr = (int*)((char*)d_ws + (512 << 10));
    int* cnt = (int*)((char*)d_ws + (512 << 10) + (4 << 20));

    fps_kernel<<<NB, 512, 0, stream>>>(pos, p4, pos_s, batch_s);
    ball_kernel<<<(NB * NM) / 4, 256, 0, stream>>>(p4, pos_s, nbr, cnt);
    mlp_kernel<<<NB * NM, 256, 0, stream>>>(x, p4, W1, B1, W2, B2, W3, B3,
                                            nbr, cnt, pos_s, out);
}

// Round 4
// 2331.627 us; speedup vs baseline: 1.6150x; 1.6150x over previous
//
#include <hip/hip_runtime.h>
#include <cstdint>
#include <cstddef>

// Problem constants (match reference)
#define NB 8          // B clouds
#define NP 4096       // N points per cloud
#define NC 64         // C feature channels
#define NM 2048       // M sampled centroids
#define NK 64         // K max neighbors
#define H1 64
#define H2 64
#define NOUT 128
#define CAND_CAP 1024
#define MSG_LD 68     // padded LDS leading dim (17*16B -> float4-aligned rows)

static __device__ __forceinline__ float sq3(float x, float y, float z) {
    // ((x*x + y*y) + z*z) with no FMA contraction, matching numpy order
    return __fadd_rn(__fadd_rn(__fmul_rn(x, x), __fmul_rn(y, y)), __fmul_rn(z, z));
}

// ---------------------------------------------------------------------------
// Kernel 1: exact FPS per cloud (8 blocks x 512 threads).
// Round-2 structure (key-only u64 shfl reduce + pts[last] broadcast read);
// in-lane 8-way argmax is a depth-3 tree (first-index tie semantics).
// ---------------------------------------------------------------------------
__global__ __launch_bounds__(512, 1)
void fps_kernel(const float* __restrict__ pos,
                float4* __restrict__ p4,
                float* __restrict__ pos_s,
                float* __restrict__ batch_s)
{
    __shared__ float4 pts[NP];                  // 64 KB
    __shared__ int s_idx[NM];                   // 8 KB
    __shared__ unsigned long long red[2][8];

    const int b = blockIdx.x;
    const int t = threadIdx.x;
    const float* p = pos + (size_t)b * NP * 3;

    for (int j = t; j < NP; j += 512) {
        float x = p[j * 3 + 0], y = p[j * 3 + 1], z = p[j * 3 + 2];
        float4 q = make_float4(x, y, z, sq3(x, y, z));
        pts[j] = q;
        p4[b * NP + j] = q;
    }
    if (t == 0) s_idx[0] = 0;
    __syncthreads();

    // thread t owns points j = t + i*512, i in 0..7 (ascending i == ascending j)
    float rx[8], ry[8], rz[8], md[8];
#pragma unroll
    for (int i = 0; i < 8; ++i) {
        float4 q = pts[t + (i << 9)];
        rx[i] = q.x; ry[i] = q.y; rz[i] = q.z;
        md[i] = __builtin_inff();
    }
    const unsigned invt = 0xFFFFFFFFu - (unsigned)t;

    int last = 0;
    for (int m = 1; m < NM; ++m) {
        const float4 L = pts[last];             // uniform broadcast read
        float vv[8];
#pragma unroll
        for (int i = 0; i < 8; ++i) {
            float dx = __fsub_rn(rx[i], L.x);
            float dy = __fsub_rn(ry[i], L.y);
            float dz = __fsub_rn(rz[i], L.z);
            float d = sq3(dx, dy, dz);
            float v = fminf(md[i], d);
            md[i] = v;
            vv[i] = v;
        }
        // depth-3 pairwise tree; strict '>' keeps the smaller index on ties,
        // left operands are lower indices -> first-max (argmax) semantics
        float nv[4]; int ni[4];
#pragma unroll
        for (int i = 0; i < 4; ++i) {
            bool c = vv[2 * i + 1] > vv[2 * i];
            nv[i] = c ? vv[2 * i + 1] : vv[2 * i];
            ni[i] = 2 * i + (c ? 1 : 0);
        }
        float mv[2]; int mi[2];
#pragma unroll
        for (int i = 0; i < 2; ++i) {
            bool c = nv[2 * i + 1] > nv[2 * i];
            mv[i] = c ? nv[2 * i + 1] : nv[2 * i];
            mi[i] = c ? ni[2 * i + 1] : ni[2 * i];
        }
        bool cf = mv[1] > mv[0];
        float bv = cf ? mv[1] : mv[0];
        int bi = cf ? mi[1] : mi[0];

        // key: larger value wins; on value tie, smaller j wins (argmax semantics)
        unsigned long long best =
            ((unsigned long long)__float_as_uint(bv) << 32) |
            (unsigned long long)(invt - (unsigned)(bi << 9));
#pragma unroll
        for (int o = 32; o > 0; o >>= 1) {
            unsigned long long other = __shfl_xor(best, o, 64);
            best = (other > best) ? other : best;
        }
        const int par = m & 1;
        if ((t & 63) == 0) red[par][t >> 6] = best;
        __syncthreads();
        unsigned long long g = red[par][0];
#pragma unroll
        for (int w = 1; w < 8; ++w) {
            unsigned long long v = red[par][w];
            g = (v > g) ? v : g;
        }
        last = (int)(0xFFFFFFFFu - (unsigned)(g & 0xFFFFFFFFull));
        if (t == 0) s_idx[m] = last;
        // red ping-pongs on parity; one barrier per iteration is race-free
    }
    __syncthreads();

    for (int m = t; m < NM; m += 512) {
        int j = s_idx[m];
        size_t o = (size_t)(b * NM + m);
        float4 q = pts[j];
        pos_s[o * 3 + 0] = q.x;
        pos_s[o * 3 + 1] = q.y;
        pos_s[o * 3 + 2] = q.z;
        batch_s[o] = (float)b;
    }
}

// ---------------------------------------------------------------------------
// Kernel 2: radius ball query + exact K-nearest-within-R set per centroid.
// One wave per centroid; 4 waves per block. Selection = binary search on the
// distance-bit threshold (output order is irrelevant: result is max-pooled).
// ---------------------------------------------------------------------------
__global__ __launch_bounds__(256, 1)
void ball_kernel(const float4* __restrict__ p4,
                 const float* __restrict__ pos_s,
                 int* __restrict__ nbr,
                 int* __restrict__ cnt_out)
{
    __shared__ unsigned long long cand[4][CAND_CAP];
    const float R2 = 0.04f;  // f32(R*R)

    const int wv = threadIdx.x >> 6;
    const int lane = threadIdx.x & 63;
    const int c = blockIdx.x * 4 + wv;         // centroid id in [0, B*M)
    const int b = c >> 11;                     // / NM
    const float4* pc = p4 + b * NP;

    const float sx = pos_s[c * 3 + 0];
    const float sy = pos_s[c * 3 + 1];
    const float sz = pos_s[c * 3 + 2];
    const float ps2 = sq3(sx, sy, sz);

    int n = 0;
    for (int j0 = 0; j0 < NP; j0 += 64) {
        int j = j0 + lane;
        float4 q = pc[j];
        float dot = __fadd_rn(__fadd_rn(__fmul_rn(sx, q.x), __fmul_rn(sy, q.y)),
                              __fmul_rn(sz, q.z));
        float d2 = __fsub_rn(__fadd_rn(ps2, q.w), __fmul_rn(2.0f, dot));
        d2 = fmaxf(d2, 0.0f);
        bool in = (d2 <= R2);
        unsigned long long mask = __ballot(in);
        if (in) {
            int off = __popcll(mask & ((1ull << lane) - 1ull));
            int slot = n + off;
            if (slot < CAND_CAP)
                cand[wv][slot] =
                    ((unsigned long long)__float_as_uint(d2) << 32) |
                    (unsigned long long)(unsigned)j;
        }
        n += __popcll(mask);
    }
    if (n > CAND_CAP) n = CAND_CAP;

    int* nb = nbr + (size_t)c * NK;
    if (n <= NK) {
        for (int i = lane; i < n; i += 64)
            nb[i] = (int)(cand[wv][i] & 0xFFFFFFFFull);
        if (lane == 0) cnt_out[c] = n;
    } else if (n <= 256) {
        // 4 register-resident candidates per lane; invalid slots = all-ones
        unsigned long long k0 = cand[wv][lane];               // n > 64 -> valid
        unsigned long long k1 = (lane + 64  < n) ? cand[wv][lane + 64]  : ~0ull;
        unsigned long long k2 = (lane + 128 < n) ? cand[wv][lane + 128] : ~0ull;
        unsigned long long k3 = (lane + 192 < n) ? cand[wv][lane + 192] : ~0ull;
        unsigned d0 = (unsigned)(k0 >> 32), d1 = (unsigned)(k1 >> 32);
        unsigned d2b = (unsigned)(k2 >> 32), d3 = (unsigned)(k3 >> 32);

        // binary search: D = 64th smallest distance-bit value
        unsigned lo = 0u, hi = __float_as_uint(R2) + 1u;  // f(lo)<64 <= f(hi)=n
        while (hi - lo > 1u) {
            unsigned mid = (lo + hi) >> 1;
            int cc = (int)(d0 < mid) + (int)(d1 < mid) +
                     (int)(d2b < mid) + (int)(d3 < mid);
            int tot = __popcll(__ballot(cc > 0)) + __popcll(__ballot(cc > 1)) +
                      __popcll(__ballot(cc > 2)) + __popcll(__ballot(cc > 3));
            if (tot >= NK) hi = mid; else lo = mid;
        }
        const unsigned D = lo;
        bool l0 = d0 < D, l1 = d1 < D, l2 = d2b < D, l3 = d3 < D;
        bool e0 = d0 == D, e1 = d1 == D, e2 = d2b == D, e3 = d3 == D;
        int mcnt = __popcll(__ballot(l0)) + __popcll(__ballot(l1)) +
                   __popcll(__ballot(l2)) + __popcll(__ballot(l3));
        int t64 = NK - mcnt;                       // take from equals, >= 1
        unsigned long long E0 = __ballot(e0), E1 = __ballot(e1);
        unsigned long long E2 = __ballot(e2), E3 = __ballot(e3);
        unsigned long long lt = (1ull << lane) - 1ull;
        int p0 = __popcll(E0), p1 = __popcll(E1), p2 = __popcll(E2);
        // equals ranked by array position == ascending point index (stable)
        bool t0 = e0 && (__popcll(E0 & lt) < t64);
        bool t1 = e1 && (p0 + __popcll(E1 & lt) < t64);
        bool t2 = e2 && (p0 + p1 + __popcll(E2 & lt) < t64);
        bool t3 = e3 && (p0 + p1 + p2 + __popcll(E3 & lt) < t64);
        bool i0 = l0 || t0, i1 = l1 || t1, i2 = l2 || t2, i3 = l3 || t3;
        unsigned long long M0 = __ballot(i0), M1 = __ballot(i1);
        unsigned long long M2 = __ballot(i2), M3 = __ballot(i3);
        int b1 = __popcll(M0), b2 = b1 + __popcll(M1), b3 = b2 + __popcll(M2);
        if (i0) nb[__popcll(M0 & lt)]      = (int)(k0 & 0xFFFFFFFFull);
        if (i1) nb[b1 + __popcll(M1 & lt)] = (int)(k1 & 0xFFFFFFFFull);
        if (i2) nb[b2 + __popcll(M2 & lt)] = (int)(k2 & 0xFFFFFFFFull);
        if (i3) nb[b3 + __popcll(M3 & lt)] = (int)(k3 & 0xFFFFFFFFull);
        if (lane == 0) cnt_out[c] = NK;
    } else {
        // fallback (unreachable for this data): 64 rounds of wave-wide min
        for (int r = 0; r < NK; ++r) {
            unsigned long long lmin = ~0ull;
            int lslot = -1;
            for (int i = lane; i < n; i += 64) {
                unsigned long long v = cand[wv][i];
                if (v < lmin) { lmin = v; lslot = i; }
            }
            unsigned long long gmin = lmin;
#pragma unroll
            for (int o = 32; o > 0; o >>= 1) {
                unsigned long long other = __shfl_xor(gmin, o, 64);
                gmin = (other < gmin) ? other : gmin;
            }
            if (lmin == gmin && lslot >= 0) {
                cand[wv][lslot] = ~0ull;
                nb[r] = (int)(gmin & 0xFFFFFFFFull);
            }
        }
        if (lane == 0) cnt_out[c] = NK;
    }
}

// ---------------------------------------------------------------------------
// Kernel 3: gather messages [x_j, pos_j - pos_i], 3-layer MLP (f32), masked
// max-pool. One block per centroid. LDS ~71 KB (hB aliases msg, W3 from L2)
// -> 2 blocks/CU.
// ---------------------------------------------------------------------------
__global__ __launch_bounds__(256, 2)
void mlp_kernel(const float* __restrict__ x,
                const float4* __restrict__ p4,
                const float* __restrict__ W1, const float* __restrict__ B1,
                const float* __restrict__ W2, const float* __restrict__ B2,
                const float* __restrict__ W3, const float* __restrict__ B3,
                const int* __restrict__ nbr, const int* __restrict__ cnt_arr,
                const float* __restrict__ pos_s,
                float* __restrict__ out)
{
    __shared__ __attribute__((aligned(16))) float sW1[67 * 64];
    __shared__ __attribute__((aligned(16))) float sW2[64 * 64];
    __shared__ float sB1[64], sB2[64], sB3[128];
    __shared__ __attribute__((aligned(16))) float msg[67 * MSG_LD]; // also hB
    __shared__ __attribute__((aligned(16))) float hA[64 * MSG_LD];
    __shared__ int obuf[128];
    __shared__ int s_nb[64];

    const int t = threadIdx.x;
    const int c = blockIdx.x;
    const int b = c >> 11;
    const int cnt = cnt_arr[c];
    float* hB = msg;   // msg is dead after layer 1; reuse for layer-2 output

    if (t < 128) obuf[t] = 0;
    if (t < 64) s_nb[t] = (t < cnt) ? nbr[(size_t)c * NK + t] : -1;
    {
        const float4* W1v = (const float4*)W1;
        const float4* W2v = (const float4*)W2;
        float4* s1 = (float4*)sW1;
        float4* s2 = (float4*)sW2;
        for (int i = t; i < 67 * 16; i += 256) s1[i] = W1v[i];
        for (int i = t; i < 64 * 16; i += 256) s2[i] = W2v[i];
    }
    if (t < 64) { sB1[t] = B1[t]; sB2[t] = B2[t]; }
    if (t < 128) sB3[t] = B3[t];
    const float sx = pos_s[c * 3 + 0];
    const float sy = pos_s[c * 3 + 1];
    const float sz = pos_s[c * 3 + 2];
    __syncthreads();

    // gather x_j -> msg[0..63][n], rel -> msg[64..66][n]
    {
        int n = t >> 2, q = t & 3;
        int j = s_nb[n];
        const float4* row = (const float4*)(x + ((size_t)b * NP + (j < 0 ? 0 : j)) * NC);
#pragma unroll
        for (int s = 0; s < 4; ++s) {
            int k4 = q * 4 + s;
            float4 v = (j >= 0) ? row[k4] : make_float4(0.f, 0.f, 0.f, 0.f);
            msg[(k4 * 4 + 0) * MSG_LD + n] = v.x;
            msg[(k4 * 4 + 1) * MSG_LD + n] = v.y;
            msg[(k4 * 4 + 2) * MSG_LD + n] = v.z;
            msg[(k4 * 4 + 3) * MSG_LD + n] = v.w;
        }
        if (t < 64) {
            int jj = s_nb[t];
            float rx = 0.f, ry = 0.f, rz = 0.f;
            if (jj >= 0) {
                float4 pj = p4[b * NP + jj];
                rx = __fsub_rn(pj.x, sx);
                ry = __fsub_rn(pj.y, sy);
                rz = __fsub_rn(pj.z, sz);
            }
            msg[64 * MSG_LD + t] = rx;
            msg[65 * MSG_LD + t] = ry;
            msg[66 * MSG_LD + t] = rz;
        }
    }
    __syncthreads();

    const int tn = (t >> 4) << 2;   // n0: 4 neighbors
    const int tf = (t & 15) << 2;   // f0: 4 features

    // ---- layer 1: [64n x 67k] @ [67k x 64f] -> hA
    {
        float acc[4][4];
#pragma unroll
        for (int i = 0; i < 4; ++i)
#pragma unroll
            for (int j = 0; j < 4; ++j) acc[i][j] = 0.f;
        for (int k = 0; k < 67; ++k) {
            float4 a = *(const float4*)&msg[k * MSG_LD + tn];
            float4 w = *(const float4*)&sW1[k * 64 + tf];
            float av[4] = {a.x, a.y, a.z, a.w};
            float wv[4] = {w.x, w.y, w.z, w.w};
#pragma unroll
            for (int i = 0; i < 4; ++i)
#pragma unroll
                for (int j = 0; j < 4; ++j)
                    acc[i][j] = fmaf(av[i], wv[j], acc[i][j]);
        }
#pragma unroll
        for (int j = 0; j < 4; ++j) {
            float bias = sB1[tf + j];
#pragma unroll
            for (int i = 0; i < 4; ++i)
                hA[(tf + j) * MSG_LD + (tn + i)] = fmaxf(acc[i][j] + bias, 0.f);
        }
    }
    __syncthreads();

    // ---- layer 2: [64n x 64k] @ [64k x 64f] -> hB (aliases msg)
    {
        float acc[4][4];
#pragma unroll
        for (int i = 0; i < 4; ++i)
#pragma unroll
            for (int j = 0; j < 4; ++j) acc[i][j] = 0.f;
        for (int k = 0; k < 64; ++k) {
            float4 a = *(const float4*)&hA[k * MSG_LD + tn];
            float4 w = *(const float4*)&sW2[k * 64 + tf];
            float av[4] = {a.x, a.y, a.z, a.w};
            float wv[4] = {w.x, w.y, w.z, w.w};
#pragma unroll
            for (int i = 0; i < 4; ++i)
#pragma unroll
                for (int j = 0; j < 4; ++j)
                    acc[i][j] = fmaf(av[i], wv[j], acc[i][j]);
        }
        __syncthreads();
#pragma unroll
        for (int j = 0; j < 4; ++j) {
            float bias = sB2[tf + j];
#pragma unroll
            for (int i = 0; i < 4; ++i)
                hB[(tf + j) * MSG_LD + (tn + i)] = fmaxf(acc[i][j] + bias, 0.f);
        }
    }
    __syncthreads();

    // ---- layer 3: [64n x 64k] @ [64k x 128f] + masked max-pool (W3 from L2)
    {
        const int tf3 = (t & 15) << 3;  // 8 features
        const float4* W3v = (const float4*)W3;
        const int wbase = (t & 15) << 1;
        float acc[4][8];
#pragma unroll
        for (int i = 0; i < 4; ++i)
#pragma unroll
            for (int j = 0; j < 8; ++j) acc[i][j] = 0.f;
#pragma unroll 4
        for (int k = 0; k < 64; ++k) {
            float4 a = *(const float4*)&hB[k * MSG_LD + tn];
            float4 w0 = W3v[k * 32 + wbase];
            float4 w1 = W3v[k * 32 + wbase + 1];
            float av[4] = {a.x, a.y, a.z, a.w};
            float wv[8] = {w0.x, w0.y, w0.z, w0.w, w1.x, w1.y, w1.z, w1.w};
#pragma unroll
            for (int i = 0; i < 4; ++i)
#pragma unroll
                for (int j = 0; j < 8; ++j)
                    acc[i][j] = fmaf(av[i], wv[j], acc[i][j]);
        }
#pragma unroll
        for (int j = 0; j < 8; ++j) {
            float bias = sB3[tf3 + j];
            float mx = -1.f;
#pragma unroll
            for (int i = 0; i < 4; ++i) {
                if (tn + i < cnt) {
                    float v = fmaxf(acc[i][j] + bias, 0.f);
                    mx = fmaxf(mx, v);
                }
            }
            if (mx >= 0.f) atomicMax(&obuf[tf3 + j], __float_as_int(mx));
        }
    }
    __syncthreads();
    if (t < 128) out[(size_t)c * NOUT + t] = __int_as_float(obuf[t]);
}

// ---------------------------------------------------------------------------
extern "C" void kernel_launch(void* const* d_in, const int* in_sizes, int n_in,
                              void* d_out, int out_size, void* d_ws, size_t ws_size,
                              hipStream_t stream)
{
    (void)in_sizes; (void)n_in; (void)out_size; (void)ws_size;
    const float* x   = (const float*)d_in[0];
    const float* pos = (const float*)d_in[1];
    // d_in[2] = batch (unused: batch[b][n] == b)
    const float* W1 = (const float*)d_in[3];
    const float* B1 = (const float*)d_in[4];
    const float* W2 = (const float*)d_in[5];
    const float* B2 = (const float*)d_in[6];
    const float* W3 = (const float*)d_in[7];
    const float* B3 = (const float*)d_in[8];

    float* out     = (float*)d_out;                       // [B,M,128]
    float* pos_s   = out + (size_t)NB * NM * NOUT;        // [B,M,3]
    float* batch_s = pos_s + (size_t)NB * NM * 3;         // [B,M]

    // workspace: p4 table (512 KB) | nbr (4 MB) | cnt (64 KB)  ~= 4.6 MB
    float4* p4 = (float4*)d_ws;
    int* nbr = (int*)((char*)d_ws + (512 << 10));
    int* cnt = (int*)((char*)d_ws + (512 << 10) + (4 << 20));

    fps_kernel<<<NB, 512, 0, stream>>>(pos, p4, pos_s, batch_s);
    ball_kernel<<<(NB * NM) / 4, 256, 0, stream>>>(p4, pos_s, nbr, cnt);
    mlp_kernel<<<NB * NM, 256, 0, stream>>>(x, p4, W1, B1, W2, B2, W3, B3,
                                            nbr, cnt, pos_s, out);
}